// Round 7
// baseline (119.629 us; speedup 1.0000x reference)
//
#include <hip/hip_runtime.h>
#include <math.h>

// EUNN layer, H=1024: 16 steps of (even + odd) pairwise complex rotations + final phase.
// v11 = v10 (packed v_pk_fma_f32 math, 42.3us) + v7's LDS double-buffered coeff
// staging (verified-neutral-at-scalar, now load-bearing).
// Post-mortem v10: VALUBusy 42->24.6% (packing worked) but dur only 52.6->42.3.
// VGPR 124->68 is the tell: 68 regs can't hold e[](64) + 16 in-flight coeff f4s ->
// the register allocator SANK the E/O prefetch loads to their uses, destroying the
// software pipeline; every phase eats the full L2/L3 round-trip + hot-set queueing
// (~5K stall cyc/step/wave) with no cover. Retro-explains v7 neutrality: at scalar
// the register prefetch was intact (VGPR=124), so staging added nothing.
// Fix: LDS staging is un-sinkable -- the ds_write + barrier for step s+1's coeffs
// is scheduled inside step s, so global latency is structurally covered; per-wave
// coeff reads become conflict-free ds_read_b128 (~120cyc, covered by compute).
//
// ws layout (f4 units): coeff_t[s][phase][512], slot k = (j&7)*64 + (j>>3) for pair j
//   (phase 0 = even pairs 0..511; phase 1 = odd pairs 0..510 + identity pad 511)
// omega (f4 = 2 elements (c,s,c,s)) transposed the same way at float offset 65536.
// cbuf read: wave lane l reads pair 8l+p at slot p*64+l (16B/lane, conflict-free).

typedef float f4 __attribute__((ext_vector_type(4)));
typedef float f2 __attribute__((ext_vector_type(2)));

#define OMCS_OFF 65536

// ---- packed-f32 rotation primitives (c = (lo,hi) coefficient pair) ----
// T = c.lo*A - c.hi*B   (per half: A/B halves travel together)
__device__ __forceinline__ f2 rot_t(f2 c, f2 A, f2 B) {
  f2 m, t;
  asm("v_pk_mul_f32 %0, %1, %2 op_sel:[1,0] op_sel_hi:[1,1]"
      : "=v"(m) : "v"(c), "v"(B));                      // (hi*B.lo, hi*B.hi)
  asm("v_pk_fma_f32 %0, %1, %2, %3 op_sel:[0,0,0] op_sel_hi:[0,1,1] "
      "neg_lo:[0,0,1] neg_hi:[0,0,1]"
      : "=v"(t) : "v"(c), "v"(A), "v"(m));              // (lo*A.lo-m.lo, lo*A.hi-m.hi)
  return t;
}
// D = (c.hi*T.lo - c.lo*T.hi, c.lo*T.lo + c.hi*T.hi)   [c=(cp,sp), T=(t0,t1)]
__device__ __forceinline__ f2 rot_d(f2 c, f2 T) {
  f2 a, d;
  asm("v_pk_mul_f32 %0, %1, %2 op_sel:[1,0] op_sel_hi:[0,0]"
      : "=v"(a) : "v"(c), "v"(T));                      // (sp*t0, cp*t0)
  asm("v_pk_fma_f32 %0, %1, %2, %3 op_sel:[0,1,0] op_sel_hi:[1,1,1] "
      "neg_lo:[1,0,0] neg_hi:[0,0,0]"
      : "=v"(d) : "v"(c), "v"(T), "v"(a));              // (-cp*t1+a.lo, sp*t1+a.hi)
  return d;
}
// O = c.hi*A + c.lo*B
__device__ __forceinline__ f2 rot_o(f2 c, f2 A, f2 B) {
  f2 m, o;
  asm("v_pk_mul_f32 %0, %1, %2 op_sel:[0,0] op_sel_hi:[0,1]"
      : "=v"(m) : "v"(c), "v"(B));                      // (lo*B.lo, lo*B.hi)
  asm("v_pk_fma_f32 %0, %1, %2, %3 op_sel:[1,0,0] op_sel_hi:[1,1,1]"
      : "=v"(o) : "v"(c), "v"(A), "v"(m));              // (hi*A.lo+m.lo, hi*A.hi+m.hi)
  return o;
}
// complex multiply V*(W.lo + i W.hi): (W.lo*V.lo - W.hi*V.hi, W.hi*V.lo + W.lo*V.hi)
__device__ __forceinline__ f2 cmulp(f2 W, f2 V) {
  f2 m, o;
  asm("v_pk_mul_f32 %0, %1, %2 op_sel:[1,1] op_sel_hi:[1,0]"
      : "=v"(m) : "v"(W), "v"(V));                      // (s*vi, s*vr)
  asm("v_pk_fma_f32 %0, %1, %2, %3 op_sel:[0,0,0] op_sel_hi:[0,1,1] "
      "neg_lo:[0,0,1] neg_hi:[0,0,0]"
      : "=v"(o) : "v"(W), "v"(V), "v"(m));              // (c*vr-m.lo, c*vi+m.hi)
  return o;
}

__global__ __launch_bounds__(256) void eunn_precompute(
    const float* __restrict__ omega, const float* __restrict__ et,
    const float* __restrict__ ot, const float* __restrict__ ep,
    const float* __restrict__ op, float* __restrict__ ws) {
  int tid = blockIdx.x * 256 + threadIdx.x;
  if (tid < 16384) {
    int s = tid >> 10, k = tid & 1023;
    int phase = k >> 9, j = k & 511;
    float ct, st, cp, sp;
    if (phase == 0) {
      sincosf(et[s * 512 + j], &st, &ct);
      sincosf(ep[s * 512 + j], &sp, &cp);
    } else if (j < 511) {
      sincosf(ot[s * 511 + j], &st, &ct);
      sincosf(op[s * 511 + j], &sp, &cp);
    } else {  // identity pad pair (elements 1023/1024)
      ct = 1.f; st = 0.f; cp = 0.f; sp = 1.f;
    }
    // transposed slot: lane = j>>3 owns pair j as its (j&7)-th register
    ((f4*)ws)[s * 1024 + phase * 512 + (j & 7) * 64 + (j >> 3)] =
        (f4){ct, st, cp, sp};
  } else if (tid < 16896) {
    int m = tid - 16384;  // f4 index covering elements 2m, 2m+1
    float s0, c0, s1, c1;
    sincosf(omega[2 * m], &s0, &c0);
    sincosf(omega[2 * m + 1], &s1, &c1);
    ((f4*)(ws + OMCS_OFF))[(m & 7) * 64 + (m >> 3)] = (f4){c0, s0, c1, s1};
  }
}

// One wave owns R rows; lane l owns elements 16l..16l+15 (8 even pairs).
// ea[r][p] = complex element 16l+2p, eb[r][p] = complex element 16l+2p+1 (f2 pairs).
// Coeffs come from a block-shared LDS double buffer; step s+1 is prefetched
// (global->reg at step top, reg->LDS + barrier at step end) while step s computes.
template <int R>
__global__ __launch_bounds__(256, 2) void eunn_main(
    const float* __restrict__ x, float* __restrict__ out,
    const float* __restrict__ ws) {
  __shared__ f4 cbuf[2][1024];  // 2 x 16KB: [step parity][transposed slot]
  const int tid = threadIdx.x;
  const int lane = tid & 63;
  const int wid = blockIdx.x * (blockDim.x >> 6) + (tid >> 6);
  const f4* wsf = (const f4*)ws;

  // ---- prologue: stage step 0 coeffs ----
  f4 p0 = wsf[tid], p1 = wsf[tid + 256], p2 = wsf[tid + 512], p3 = wsf[tid + 768];

  f2 ea[R][8], eb[R][8];
#pragma unroll
  for (int r = 0; r < R; ++r) {
    const f4* xr = (const f4*)(x + (size_t)(wid * R + r) * 2048) + lane * 8;
#pragma unroll
    for (int p = 0; p < 8; ++p) {
      f4 t = xr[p];
      ea[r][p] = (f2){t.x, t.y};
      eb[r][p] = (f2){t.z, t.w};
    }
  }

  cbuf[0][tid] = p0;
  cbuf[0][tid + 256] = p1;
  cbuf[0][tid + 512] = p2;
  cbuf[0][tid + 768] = p3;
  __syncthreads();

#pragma unroll 1
  for (int s = 0; s < 16; ++s) {
    const int cur = s & 1, nxt = cur ^ 1;
    // ---- issue next step's staging loads (committed at step end) ----
    const f4* nb = wsf + ((s + 1) & 15) * 1024;
    f4 n0 = nb[tid], n1 = nb[tid + 256], n2 = nb[tid + 512], n3 = nb[tid + 768];

    // ---- read this step's coeffs from LDS (conflict-free ds_read_b128) ----
    f4 E[8], O[8];
#pragma unroll
    for (int p = 0; p < 8; ++p) E[p] = cbuf[cur][p * 64 + lane];
#pragma unroll
    for (int p = 0; p < 8; ++p) O[p] = cbuf[cur][512 + p * 64 + lane];

    // ---- even rotation: pair j=8l+p couples ea[p] and eb[p] ----
#pragma unroll
    for (int r = 0; r < R; ++r) {
#pragma unroll
      for (int p = 0; p < 8; ++p) {
        f2 cxy = (f2){E[p].x, E[p].y};   // (ct, st)
        f2 czw = (f2){E[p].z, E[p].w};   // (cp, sp)
        f2 a = ea[r][p], b = eb[r][p];
        f2 T = rot_t(cxy, a, b);         // ct*a - st*b
        ea[r][p] = rot_d(czw, T);        // (sp*t0-cp*t1, cp*t0+sp*t1)
        eb[r][p] = rot_o(cxy, a, b);     // st*a + ct*b
      }
    }

    // ---- odd rotation: pair j couples elements 2j+1, 2j+2 ----
    {
      // neighbor pair (8l-1)'s (ct,st) from lane l-1; identity at lane 0
      float ctm = __shfl_up(O[7].x, 1, 64);
      float stm = __shfl_up(O[7].y, 1, 64);
      if (lane == 0) { ctm = 1.f; stm = 0.f; }
      f2 cm2 = (f2){ctm, stm};
#pragma unroll
      for (int r = 0; r < R; ++r) {
        float upx = __shfl_down(ea[r][0].x, 1, 64);  // elem 16l+16 (pre)
        float upy = __shfl_down(ea[r][0].y, 1, 64);
        float dnz = __shfl_up(eb[r][7].x, 1, 64);    // elem 16l-1 (pre)
        float dnw = __shfl_up(eb[r][7].y, 1, 64);
        // element 16l = second half of pair 8l-1: stm*D + ctm*X
        f2 D = (f2){dnz, dnw};
        ea[r][0] = rot_o(cm2, D, ea[r][0]);
        // interior odd pairs j=8l+p, p=0..6: couples eb[p] and ea[p+1]
#pragma unroll
        for (int p = 0; p < 7; ++p) {
          f2 oxy = (f2){O[p].x, O[p].y};
          f2 ozw = (f2){O[p].z, O[p].w};
          f2 A = eb[r][p], B = ea[r][p + 1];
          f2 T = rot_t(oxy, A, B);
          eb[r][p] = rot_d(ozw, T);
          ea[r][p + 1] = rot_o(oxy, A, B);
        }
        // boundary pair j=8l+7 (second element lives in lane l+1; lane 63 = identity)
        {
          f2 oxy = (f2){O[7].x, O[7].y};
          f2 ozw = (f2){O[7].z, O[7].w};
          f2 UP = (f2){upx, upy};
          f2 T = rot_t(oxy, eb[r][7], UP);
          eb[r][7] = rot_d(ozw, T);
        }
      }
    }

    // ---- commit next step's coeffs to the other buffer (un-sinkable) ----
    cbuf[nxt][tid] = n0;
    cbuf[nxt][tid + 256] = n1;
    cbuf[nxt][tid + 512] = n2;
    cbuf[nxt][tid + 768] = n3;
    __syncthreads();
  }

  // ---- final diagonal phase + store ----
  const f4* om4 = (const f4*)(ws + OMCS_OFF) + lane;  // (c,s,c,s), + p*64
#pragma unroll
  for (int r = 0; r < R; ++r) {
    f4* outr = (f4*)(out + (size_t)(wid * R + r) * 2048) + lane * 8;
#pragma unroll
    for (int p = 0; p < 8; ++p) {
      f4 w = om4[p * 64];
      f2 o1 = cmulp((f2){w.x, w.y}, ea[r][p]);
      f2 o2 = cmulp((f2){w.z, w.w}, eb[r][p]);
      outr[p] = (f4){o1.x, o1.y, o2.x, o2.y};
    }
  }
}

extern "C" void kernel_launch(void* const* d_in, const int* in_sizes, int n_in,
                              void* d_out, int out_size, void* d_ws, size_t ws_size,
                              hipStream_t stream) {
  const float* x     = (const float*)d_in[0];  // (4096,1024,2)
  const float* omega = (const float*)d_in[1];  // (1024,)
  const float* et    = (const float*)d_in[2];  // (16,512)
  const float* ot    = (const float*)d_in[3];  // (16,511)
  const float* ep    = (const float*)d_in[4];  // (16,512)
  const float* op    = (const float*)d_in[5];  // (16,511)
  float* out = (float*)d_out;
  float* ws  = (float*)d_ws;

  // 16896 jobs: 16x1024 coeff quads + 512 omega f4 entries
  eunn_precompute<<<dim3(66), dim3(256), 0, stream>>>(omega, et, ot, ep, op, ws);

  // R=2 rows/wave: 2048 waves, 4 waves/block -> 512 blocks (2/CU, 8 waves/CU)
  eunn_main<2><<<dim3(512), dim3(256), 0, stream>>>(x, out, ws);
}

// Round 8
// 118.903 us; speedup vs baseline: 1.0061x; 1.0061x over previous
//
#include <hip/hip_runtime.h>
#include <math.h>

// EUNN layer, H=1024: 16 steps of (even + odd) pairwise complex rotations + final phase.
// v12 = v10 (packed v_pk math, 42.3us best) + coeff staging via global_load_lds DMA.
// Post-mortem v11: LDS staging regressed because the reg-staged n0..n3 pushed
// liveness past what the allocator kept (VGPR=76) -> scratch spills (WRITE_SIZE
// 43->62MB). So v11 tested staging+spills, not staging. v12 stages with
// __builtin_amdgcn_global_load_lds: direct global->LDS, NO VGPR liveness, and one
// block-wide coeff copy per step (256 lines/step/block) replaces 8 per-wave copies
// (2048 lines/step/CU) -> 4x fewer TA transactions on the dominant traffic term.
// Theory: stall (~75K cyc/SIMD, invariant across v4/v10) = per-CU TA/L1 transaction
// throughput, 2/3 of which is redundant per-wave coeff re-reads.
//
// ws layout (f4 units): coeff_t[s][phase][512], slot k = (j&7)*64 + (j>>3) for pair j
//   (phase 0 = even pairs 0..511; phase 1 = odd pairs 0..510 + identity pad 511)
// omega (f4 = 2 elements (c,s,c,s)) transposed the same way at float offset 65536.
// cbuf read: wave lane l reads pair 8l+p at slot p*64+l (16B/lane, conflict-free).
// stage: thread tid covers slots {tid, tid+256, tid+512, tid+768}; per wave each
// chunk is base + lane*16B contiguous = exactly global_load_lds's dest pattern.

typedef float f4 __attribute__((ext_vector_type(4)));
typedef float f2 __attribute__((ext_vector_type(2)));

#define OMCS_OFF 65536

// ---- packed-f32 rotation primitives (c = (lo,hi) coefficient pair) ----
// T = c.lo*A - c.hi*B   (per half: A/B halves travel together)
__device__ __forceinline__ f2 rot_t(f2 c, f2 A, f2 B) {
  f2 m, t;
  asm("v_pk_mul_f32 %0, %1, %2 op_sel:[1,0] op_sel_hi:[1,1]"
      : "=v"(m) : "v"(c), "v"(B));                      // (hi*B.lo, hi*B.hi)
  asm("v_pk_fma_f32 %0, %1, %2, %3 op_sel:[0,0,0] op_sel_hi:[0,1,1] "
      "neg_lo:[0,0,1] neg_hi:[0,0,1]"
      : "=v"(t) : "v"(c), "v"(A), "v"(m));              // (lo*A.lo-m.lo, lo*A.hi-m.hi)
  return t;
}
// D = (c.hi*T.lo - c.lo*T.hi, c.lo*T.lo + c.hi*T.hi)   [c=(cp,sp), T=(t0,t1)]
__device__ __forceinline__ f2 rot_d(f2 c, f2 T) {
  f2 a, d;
  asm("v_pk_mul_f32 %0, %1, %2 op_sel:[1,0] op_sel_hi:[0,0]"
      : "=v"(a) : "v"(c), "v"(T));                      // (sp*t0, cp*t0)
  asm("v_pk_fma_f32 %0, %1, %2, %3 op_sel:[0,1,0] op_sel_hi:[1,1,1] "
      "neg_lo:[1,0,0] neg_hi:[0,0,0]"
      : "=v"(d) : "v"(c), "v"(T), "v"(a));              // (-cp*t1+a.lo, sp*t1+a.hi)
  return d;
}
// O = c.hi*A + c.lo*B
__device__ __forceinline__ f2 rot_o(f2 c, f2 A, f2 B) {
  f2 m, o;
  asm("v_pk_mul_f32 %0, %1, %2 op_sel:[0,0] op_sel_hi:[0,1]"
      : "=v"(m) : "v"(c), "v"(B));                      // (lo*B.lo, lo*B.hi)
  asm("v_pk_fma_f32 %0, %1, %2, %3 op_sel:[1,0,0] op_sel_hi:[1,1,1]"
      : "=v"(o) : "v"(c), "v"(A), "v"(m));              // (hi*A.lo+m.lo, hi*A.hi+m.hi)
  return o;
}
// complex multiply V*(W.lo + i W.hi): (W.lo*V.lo - W.hi*V.hi, W.hi*V.lo + W.lo*V.hi)
__device__ __forceinline__ f2 cmulp(f2 W, f2 V) {
  f2 m, o;
  asm("v_pk_mul_f32 %0, %1, %2 op_sel:[1,1] op_sel_hi:[1,0]"
      : "=v"(m) : "v"(W), "v"(V));                      // (s*vi, s*vr)
  asm("v_pk_fma_f32 %0, %1, %2, %3 op_sel:[0,0,0] op_sel_hi:[0,1,1] "
      "neg_lo:[0,0,1] neg_hi:[0,0,0]"
      : "=v"(o) : "v"(W), "v"(V), "v"(m));              // (c*vr-m.lo, c*vi+m.hi)
  return o;
}

__global__ __launch_bounds__(256) void eunn_precompute(
    const float* __restrict__ omega, const float* __restrict__ et,
    const float* __restrict__ ot, const float* __restrict__ ep,
    const float* __restrict__ op, float* __restrict__ ws) {
  int tid = blockIdx.x * 256 + threadIdx.x;
  if (tid < 16384) {
    int s = tid >> 10, k = tid & 1023;
    int phase = k >> 9, j = k & 511;
    float ct, st, cp, sp;
    if (phase == 0) {
      sincosf(et[s * 512 + j], &st, &ct);
      sincosf(ep[s * 512 + j], &sp, &cp);
    } else if (j < 511) {
      sincosf(ot[s * 511 + j], &st, &ct);
      sincosf(op[s * 511 + j], &sp, &cp);
    } else {  // identity pad pair (elements 1023/1024)
      ct = 1.f; st = 0.f; cp = 0.f; sp = 1.f;
    }
    // transposed slot: lane = j>>3 owns pair j as its (j&7)-th register
    ((f4*)ws)[s * 1024 + phase * 512 + (j & 7) * 64 + (j >> 3)] =
        (f4){ct, st, cp, sp};
  } else if (tid < 16896) {
    int m = tid - 16384;  // f4 index covering elements 2m, 2m+1
    float s0, c0, s1, c1;
    sincosf(omega[2 * m], &s0, &c0);
    sincosf(omega[2 * m + 1], &s1, &c1);
    ((f4*)(ws + OMCS_OFF))[(m & 7) * 64 + (m >> 3)] = (f4){c0, s0, c1, s1};
  }
}

// Stage one step's 16KB coeff block into LDS via direct global->LDS DMA.
// Per chunk k: wave-uniform dest base + lane*16B; global src lane-consecutive.
__device__ __forceinline__ void stage_step(const f4* nb, f4* dst, int tid) {
#pragma unroll
  for (int k = 0; k < 4; ++k) {
    __builtin_amdgcn_global_load_lds(
        (const __attribute__((address_space(1))) void*)(nb + k * 256 + tid),
        (__attribute__((address_space(3))) void*)(dst + k * 256 + (tid & 192)),
        16, 0, 0);
  }
}

// One wave owns R rows; lane l owns elements 16l..16l+15 (8 even pairs).
// ea[r][p] = complex element 16l+2p, eb[r][p] = complex element 16l+2p+1 (f2 pairs).
// Coeffs: block-shared LDS double buffer, filled by global_load_lds one step ahead;
// the end-of-step __syncthreads (vmcnt(0)+lgkmcnt(0) drain) publishes the DMA.
template <int R>
__global__ __launch_bounds__(256, 2) void eunn_main(
    const float* __restrict__ x, float* __restrict__ out,
    const float* __restrict__ ws) {
  __shared__ f4 cbuf[2][1024];  // 2 x 16KB: [step parity][transposed slot]
  const int tid = threadIdx.x;
  const int lane = tid & 63;
  const int wid = blockIdx.x * (blockDim.x >> 6) + (tid >> 6);
  const f4* wsf = (const f4*)ws;

  // ---- prologue: DMA step-0 coeffs, overlap with x loads ----
  stage_step(wsf, cbuf[0], tid);

  f2 ea[R][8], eb[R][8];
#pragma unroll
  for (int r = 0; r < R; ++r) {
    const f4* xr = (const f4*)(x + (size_t)(wid * R + r) * 2048) + lane * 8;
#pragma unroll
    for (int p = 0; p < 8; ++p) {
      f4 t = xr[p];
      ea[r][p] = (f2){t.x, t.y};
      eb[r][p] = (f2){t.z, t.w};
    }
  }
  __syncthreads();

#pragma unroll 1
  for (int s = 0; s < 16; ++s) {
    const int cur = s & 1;
    // ---- DMA next step's coeffs into the other buffer (zero VGPR cost) ----
    if (s < 15) stage_step(wsf + (s + 1) * 1024, cbuf[cur ^ 1], tid);

    // ---- read this step's coeffs from LDS (conflict-free ds_read_b128) ----
    f4 E[8], O[8];
#pragma unroll
    for (int p = 0; p < 8; ++p) E[p] = cbuf[cur][p * 64 + lane];
#pragma unroll
    for (int p = 0; p < 8; ++p) O[p] = cbuf[cur][512 + p * 64 + lane];

    // ---- even rotation: pair j=8l+p couples ea[p] and eb[p] ----
#pragma unroll
    for (int r = 0; r < R; ++r) {
#pragma unroll
      for (int p = 0; p < 8; ++p) {
        f2 cxy = (f2){E[p].x, E[p].y};   // (ct, st)
        f2 czw = (f2){E[p].z, E[p].w};   // (cp, sp)
        f2 a = ea[r][p], b = eb[r][p];
        f2 T = rot_t(cxy, a, b);         // ct*a - st*b
        ea[r][p] = rot_d(czw, T);        // (sp*t0-cp*t1, cp*t0+sp*t1)
        eb[r][p] = rot_o(cxy, a, b);     // st*a + ct*b
      }
    }

    // ---- odd rotation: pair j couples elements 2j+1, 2j+2 ----
    {
      // neighbor pair (8l-1)'s (ct,st) from lane l-1; identity at lane 0
      float ctm = __shfl_up(O[7].x, 1, 64);
      float stm = __shfl_up(O[7].y, 1, 64);
      if (lane == 0) { ctm = 1.f; stm = 0.f; }
      f2 cm2 = (f2){ctm, stm};
#pragma unroll
      for (int r = 0; r < R; ++r) {
        float upx = __shfl_down(ea[r][0].x, 1, 64);  // elem 16l+16 (pre)
        float upy = __shfl_down(ea[r][0].y, 1, 64);
        float dnz = __shfl_up(eb[r][7].x, 1, 64);    // elem 16l-1 (pre)
        float dnw = __shfl_up(eb[r][7].y, 1, 64);
        // element 16l = second half of pair 8l-1: stm*D + ctm*X
        f2 D = (f2){dnz, dnw};
        ea[r][0] = rot_o(cm2, D, ea[r][0]);
        // interior odd pairs j=8l+p, p=0..6: couples eb[p] and ea[p+1]
#pragma unroll
        for (int p = 0; p < 7; ++p) {
          f2 oxy = (f2){O[p].x, O[p].y};
          f2 ozw = (f2){O[p].z, O[p].w};
          f2 A = eb[r][p], B = ea[r][p + 1];
          f2 T = rot_t(oxy, A, B);
          eb[r][p] = rot_d(ozw, T);
          ea[r][p + 1] = rot_o(oxy, A, B);
        }
        // boundary pair j=8l+7 (second element lives in lane l+1; lane 63 = identity)
        {
          f2 oxy = (f2){O[7].x, O[7].y};
          f2 ozw = (f2){O[7].z, O[7].w};
          f2 UP = (f2){upx, upy};
          f2 T = rot_t(oxy, eb[r][7], UP);
          eb[r][7] = rot_d(ozw, T);
        }
      }
    }

    // ---- publish next step's DMA'd coeffs (vmcnt(0)+barrier) ----
    if (s < 15) __syncthreads();
  }

  // ---- final diagonal phase + store ----
  const f4* om4 = (const f4*)(ws + OMCS_OFF) + lane;  // (c,s,c,s), + p*64
#pragma unroll
  for (int r = 0; r < R; ++r) {
    f4* outr = (f4*)(out + (size_t)(wid * R + r) * 2048) + lane * 8;
#pragma unroll
    for (int p = 0; p < 8; ++p) {
      f4 w = om4[p * 64];
      f2 o1 = cmulp((f2){w.x, w.y}, ea[r][p]);
      f2 o2 = cmulp((f2){w.z, w.w}, eb[r][p]);
      outr[p] = (f4){o1.x, o1.y, o2.x, o2.y};
    }
  }
}

extern "C" void kernel_launch(void* const* d_in, const int* in_sizes, int n_in,
                              void* d_out, int out_size, void* d_ws, size_t ws_size,
                              hipStream_t stream) {
  const float* x     = (const float*)d_in[0];  // (4096,1024,2)
  const float* omega = (const float*)d_in[1];  // (1024,)
  const float* et    = (const float*)d_in[2];  // (16,512)
  const float* ot    = (const float*)d_in[3];  // (16,511)
  const float* ep    = (const float*)d_in[4];  // (16,512)
  const float* op    = (const float*)d_in[5];  // (16,511)
  float* out = (float*)d_out;
  float* ws  = (float*)d_ws;

  // 16896 jobs: 16x1024 coeff quads + 512 omega f4 entries
  eunn_precompute<<<dim3(66), dim3(256), 0, stream>>>(omega, et, ot, ep, op, ws);

  // R=2 rows/wave: 2048 waves, 4 waves/block -> 512 blocks (2/CU, 8 waves/CU)
  eunn_main<2><<<dim3(512), dim3(256), 0, stream>>>(x, out, ws);
}